// Round 27
// baseline (6232.486 us; speedup 1.0000x reference)
//
#include <hip/hip_runtime.h>
#include <hip/hip_bf16.h>

// PartCodeTransformer forward on MI355X (gfx950).
// I/O fp32; internal bf16 MFMA + fp32 accum/residual.
// Round 27: FF merged to full-batch (-24 dispatches). FF-mid [32768x2048] bf16 split:
// rows [0,16K) in sc (out_h 64 MiB), rows [16K,32K) in buf2 (64 MiB ws). vt aliases
// buf2's lower 32 MiB (time-disjoint: vt live qkv->attn; FF-mid live fc->fcp).
// gemm_bt2 EPI=5 = gelu + split-write; gemm_bt1 A2 = split-read. 16384 % 256 == 0 so
// the half-branch is tile-uniform. All else identical to round 26.

typedef unsigned short u16;
typedef unsigned int u32;
typedef __attribute__((ext_vector_type(8))) short bf16x8;
typedef __attribute__((ext_vector_type(8))) unsigned short us8;
typedef __attribute__((ext_vector_type(4))) unsigned short us4;
typedef __attribute__((ext_vector_type(4))) float f32x4;

__device__ __forceinline__ float bf2f(u16 s) {
  union { u32 u; float f; } c; c.u = ((u32)s) << 16; return c.f;
}
__device__ __forceinline__ u16 f2bf(float f) {
  __hip_bfloat16 h = __float2bfloat16(f);   // hardware RNE cvt
  union { __hip_bfloat16 h; u16 u; } c; c.h = h; return c.u;
}
__device__ __forceinline__ float gelu_f(float v) {
  return 0.5f * v * (1.0f + erff(v * 0.7071067811865475f));
}
__device__ __forceinline__ void gl2lds16(const u16* g, u16* l) {
  __builtin_amdgcn_global_load_lds((const __attribute__((address_space(1))) void*)g,
                                   (__attribute__((address_space(3))) void*)l, 16, 0, 0);
}
__device__ __forceinline__ f32x4 mfma16(bf16x8 a, bf16x8 b, f32x4 c) {
  return __builtin_amdgcn_mfma_f32_16x16x32_bf16(a, b, c, 0, 0, 0);
}
__device__ __forceinline__ float exp2_f(float x) { return __builtin_amdgcn_exp2f(x); }
// chunk swizzle for 128B rows (attn K/V): permute 16B chunks within the row
__device__ __forceinline__ int swz(int row) { return (row ^ (row >> 3)) & 7; }

// ------------- A[M,K](lda) x Bt[N,K](ldb) GEMM, 256x128 tile, 8 waves, 2-phase dbuf -------------
// LDS swizzle: phys_chunk = log_chunk ^ ((row>>1)&3).
// EPI: 0 f32=v ; 1 bf16=v ; 2 f32+=v ; 3 bf16=gelu(v)
// EPI 4 (qkv): Q(x0.125*log2e)/K packed -> Cb[row*1024 + hh*128 + off]; V -> Vt transposed.
template <int EPI>
__global__ __launch_bounds__(512)
void gemm_bt(const u16* __restrict__ A, const u16* __restrict__ Bt,
             const float* __restrict__ bias, float* __restrict__ Cf,
             u16* __restrict__ Cb, u16* __restrict__ Vt, int K, int lda, int ldb, int ldc)
{
  __shared__ __align__(16) u16 As[2][256 * 32];   // 32 KB
  __shared__ __align__(16) u16 Bs[2][128 * 32];   // 16 KB
  const int tid = threadIdx.x;
  const int lane = tid & 63, wid = tid >> 6;
  const int wm = wid & 3, wn = wid >> 2;          // 4 M-waves x 2 N-waves
  const int nbx = gridDim.x;
  const int nwg = nbx * gridDim.y;
  int lin = blockIdx.y * nbx + blockIdx.x;
  lin = (lin & 7) * (nwg >> 3) + (lin >> 3);
  const long m0 = (long)(lin / nbx) * 256, n0 = (long)(lin % nbx) * 128;

  const int c0 = tid, c1 = tid + 512;
  const int kc0 = (c0 & 3) ^ (((c0 >> 2) >> 1) & 3);
  const int kc1 = (c1 & 3) ^ (((c1 >> 2) >> 1) & 3);
  const int kcb = (tid & 3) ^ (((tid >> 2) >> 1) & 3);
  const u16* aS0 = A + (m0 + (c0 >> 2)) * (long)lda + kc0 * 8;
  const u16* aS1 = A + (m0 + (c1 >> 2)) * (long)lda + kc1 * 8;
  const u16* bS0 = Bt + (n0 + (tid >> 2)) * (long)ldb + kcb * 8;

  f32x4 acc[4][4] = {};
  const int cl4 = lane & 15;
  const int gph = ((lane >> 4) ^ ((cl4 >> 1) & 3)) * 8;
  const int aro = (wm * 64 + cl4) * 32 + gph;
  const int bro = (wn * 64 + cl4) * 32 + gph;
  const int nt = K >> 5;

#define STAGE_AB(buf, k0_)                          \
  gl2lds16(aS0 + (k0_), As[buf] + c0 * 8);          \
  gl2lds16(aS1 + (k0_), As[buf] + c1 * 8);          \
  gl2lds16(bS0 + (k0_), Bs[buf] + tid * 8);

  STAGE_AB(0, 0);
  for (int t = 0; t < nt; ++t) {
    const int cur = t & 1;
    if (t < nt - 1) {
      STAGE_AB(cur ^ 1, (t + 1) * 32);
      asm volatile("s_waitcnt vmcnt(3)" ::: "memory");
    } else {
      asm volatile("s_waitcnt vmcnt(0)" ::: "memory");
    }
    __builtin_amdgcn_s_barrier();
    bf16x8 af[4], bfr[4];
#pragma unroll
    for (int i = 0; i < 4; ++i) af[i] = *(const bf16x8*)(As[cur] + aro + i * 16 * 32);
#pragma unroll
    for (int j = 0; j < 4; ++j) bfr[j] = *(const bf16x8*)(Bs[cur] + bro + j * 16 * 32);
    __builtin_amdgcn_s_setprio(1);
#pragma unroll
    for (int i = 0; i < 4; ++i)
#pragma unroll
      for (int j = 0; j < 4; ++j)
        acc[i][j] = mfma16(af[i], bfr[j], acc[i][j]);
    __builtin_amdgcn_s_setprio(0);
    __builtin_amdgcn_s_barrier();
  }
#undef STAGE_AB
  const int rg = (lane >> 4) * 4, cl = lane & 15;
#pragma unroll
  for (int i = 0; i < 4; ++i) {
#pragma unroll
    for (int j = 0; j < 4; ++j) {
      const long row = m0 + wm * 64 + i * 16 + rg;
      const long col = n0 + wn * 64 + j * 16 + cl;
      const float bv = bias ? bias[col] : 0.0f;
      if (EPI == 4) {
        const int hh = (int)col / 192, off = (int)col - hh * 192;
        if (off < 64) {       // Q: pre-scale by 0.125*log2(e) (softmax in log2 domain)
#pragma unroll
          for (int r = 0; r < 4; ++r)
            Cb[(row + r) * ldc + hh * 128 + off] = f2bf((acc[i][j][r] + bv) * 0.1803368801111244f);
        } else if (off < 128) {  // K
#pragma unroll
          for (int r = 0; r < 4; ++r)
            Cb[(row + r) * ldc + hh * 128 + off] = f2bf(acc[i][j][r] + bv);
        } else {              // V -> transposed vt
          us4 pk;
#pragma unroll
          for (int r = 0; r < 4; ++r) pk[r] = f2bf(acc[i][j][r] + bv);
          const long bl = row >> 10, t0 = row & 1023;
          *(us4*)(Vt + (((bl * 8 + hh) * 64 + (off - 128)) << 10) + t0) = pk;
        }
      } else {
#pragma unroll
        for (int r = 0; r < 4; ++r) {
          float v = acc[i][j][r] + bv;
          long idx = (row + r) * ldc + col;
          if (EPI == 0) Cf[idx] = v;
          else if (EPI == 1) Cb[idx] = f2bf(v);
          else if (EPI == 2) Cf[idx] += v;
          else Cb[idx] = f2bf(gelu_f(v));
        }
      }
    }
  }
}

// ------------- 128x128 tile, 4 waves (256 thr), 2-phase dbuf — for fcp (full batch) -------------
// A2: if non-null, rows >= 16384 of A are read from A2 (local row = row - 16384).
template <int EPI>
__global__ __launch_bounds__(256)
void gemm_bt1(const u16* __restrict__ A, const u16* __restrict__ A2,
              const u16* __restrict__ Bt,
              const float* __restrict__ bias, float* __restrict__ Cf,
              u16* __restrict__ Cb, int K, int lda, int ldb, int ldc)
{
  __shared__ __align__(16) u16 As[2][128 * 32];   // 16 KB
  __shared__ __align__(16) u16 Bs[2][128 * 32];   // 16 KB
  const int tid = threadIdx.x;
  const int lane = tid & 63, wid = tid >> 6;
  const int wm = wid >> 1, wn = wid & 1;          // 2x2 waves, 64x64 each
  const int nbx = gridDim.x;
  const int nwg = nbx * gridDim.y;
  int lin = blockIdx.y * nbx + blockIdx.x;
  lin = (lin & 7) * (nwg >> 3) + (lin >> 3);
  const long m0 = (long)(lin / nbx) * 128, n0 = (long)(lin % nbx) * 128;

  // A-base select (tile-uniform: 16384 % 128 == 0)
  const u16* Ab = A;
  long m0a = m0;
  if (A2 && m0 >= 16384) { Ab = A2; m0a = m0 - 16384; }

  const int c0 = tid, c1 = tid + 256;
  const int kc0 = (c0 & 3) ^ (((c0 >> 2) >> 1) & 3);
  const int kc1 = (c1 & 3) ^ (((c1 >> 2) >> 1) & 3);
  const u16* aS0 = Ab + (m0a + (c0 >> 2)) * (long)lda + kc0 * 8;
  const u16* aS1 = Ab + (m0a + (c1 >> 2)) * (long)lda + kc1 * 8;
  const u16* bS0 = Bt + (n0 + (c0 >> 2)) * (long)ldb + kc0 * 8;
  const u16* bS1 = Bt + (n0 + (c1 >> 2)) * (long)ldb + kc1 * 8;

  f32x4 acc[4][4] = {};
  const int cl4 = lane & 15;
  const int gph = ((lane >> 4) ^ ((cl4 >> 1) & 3)) * 8;
  const int aro = (wm * 64 + cl4) * 32 + gph;
  const int bro = (wn * 64 + cl4) * 32 + gph;
  const int nt = K >> 5;

#define STAGE_AB1(buf, k0_)                         \
  gl2lds16(aS0 + (k0_), As[buf] + c0 * 8);          \
  gl2lds16(aS1 + (k0_), As[buf] + c1 * 8);          \
  gl2lds16(bS0 + (k0_), Bs[buf] + c0 * 8);          \
  gl2lds16(bS1 + (k0_), Bs[buf] + c1 * 8);

  STAGE_AB1(0, 0);
  for (int t = 0; t < nt; ++t) {
    const int cur = t & 1;
    if (t < nt - 1) {
      STAGE_AB1(cur ^ 1, (t + 1) * 32);
      asm volatile("s_waitcnt vmcnt(4)" ::: "memory");
    } else {
      asm volatile("s_waitcnt vmcnt(0)" ::: "memory");
    }
    __builtin_amdgcn_s_barrier();
    bf16x8 af[4], bfr[4];
#pragma unroll
    for (int i = 0; i < 4; ++i) af[i] = *(const bf16x8*)(As[cur] + aro + i * 16 * 32);
#pragma unroll
    for (int j = 0; j < 4; ++j) bfr[j] = *(const bf16x8*)(Bs[cur] + bro + j * 16 * 32);
    __builtin_amdgcn_s_setprio(1);
#pragma unroll
    for (int i = 0; i < 4; ++i)
#pragma unroll
      for (int j = 0; j < 4; ++j)
        acc[i][j] = mfma16(af[i], bfr[j], acc[i][j]);
    __builtin_amdgcn_s_setprio(0);
    __builtin_amdgcn_s_barrier();
  }
#undef STAGE_AB1
  const int rg = (lane >> 4) * 4, cl = lane & 15;
#pragma unroll
  for (int i = 0; i < 4; ++i) {
#pragma unroll
    for (int j = 0; j < 4; ++j) {
      const long row = m0 + wm * 64 + i * 16 + rg;
      const long col = n0 + wn * 64 + j * 16 + cl;
      const float bv = bias ? bias[col] : 0.0f;
#pragma unroll
      for (int r = 0; r < 4; ++r) {
        float v = acc[i][j][r] + bv;
        long idx = (row + r) * ldc + col;
        if (EPI == 0) Cf[idx] = v;
        else if (EPI == 1) Cb[idx] = f2bf(v);
        else if (EPI == 2) Cf[idx] += v;
        else Cb[idx] = f2bf(gelu_f(v));
      }
    }
  }
}

// ------------- 256x256 tile, 16 waves (1024 thr), 2-phase dbuf — for fc -------------
// EPI 3: bf16=gelu(v) -> Cb. EPI 5: gelu, rows<16384 -> Cb, rows>=16384 -> Cb2 (row-16384).
template <int EPI>
__global__ __launch_bounds__(1024)
void gemm_bt2(const u16* __restrict__ A, const u16* __restrict__ Bt,
              const float* __restrict__ bias, float* __restrict__ Cf,
              u16* __restrict__ Cb, u16* __restrict__ Cb2, int K, int lda, int ldb, int ldc)
{
  __shared__ __align__(16) u16 As[2][256 * 32];   // 32 KB
  __shared__ __align__(16) u16 Bs[2][256 * 32];   // 32 KB
  const int tid = threadIdx.x;
  const int lane = tid & 63, wid = tid >> 6;
  const int wm = wid & 3, wn = wid >> 2;          // 4x4 waves
  const int nbx = gridDim.x;
  const int nwg = nbx * gridDim.y;
  int lin = blockIdx.y * nbx + blockIdx.x;
  lin = (lin & 7) * (nwg >> 3) + (lin >> 3);
  const long m0 = (long)(lin / nbx) * 256, n0 = (long)(lin % nbx) * 256;

  const int kcA = (tid & 3) ^ (((tid >> 2) >> 1) & 3);
  const u16* aS0 = A + (m0 + (tid >> 2)) * (long)lda + kcA * 8;
  const u16* bS0 = Bt + (n0 + (tid >> 2)) * (long)ldb + kcA * 8;

  f32x4 acc[4][4] = {};
  const int cl4 = lane & 15;
  const int gph = ((lane >> 4) ^ ((cl4 >> 1) & 3)) * 8;
  const int aro = (wm * 64 + cl4) * 32 + gph;
  const int bro = (wn * 64 + cl4) * 32 + gph;
  const int nt = K >> 5;

#define STAGE_AB2(buf, k0_)                         \
  gl2lds16(aS0 + (k0_), As[buf] + tid * 8);         \
  gl2lds16(bS0 + (k0_), Bs[buf] + tid * 8);

  STAGE_AB2(0, 0);
  for (int t = 0; t < nt; ++t) {
    const int cur = t & 1;
    if (t < nt - 1) {
      STAGE_AB2(cur ^ 1, (t + 1) * 32);
      asm volatile("s_waitcnt vmcnt(2)" ::: "memory");
    } else {
      asm volatile("s_waitcnt vmcnt(0)" ::: "memory");
    }
    __builtin_amdgcn_s_barrier();
    bf16x8 af[4], bfr[4];
#pragma unroll
    for (int i = 0; i < 4; ++i) af[i] = *(const bf16x8*)(As[cur] + aro + i * 16 * 32);
#pragma unroll
    for (int j = 0; j < 4; ++j) bfr[j] = *(const bf16x8*)(Bs[cur] + bro + j * 16 * 32);
    __builtin_amdgcn_s_setprio(1);
#pragma unroll
    for (int i = 0; i < 4; ++i)
#pragma unroll
      for (int j = 0; j < 4; ++j)
        acc[i][j] = mfma16(af[i], bfr[j], acc[i][j]);
    __builtin_amdgcn_s_setprio(0);
    __builtin_amdgcn_s_barrier();
  }
#undef STAGE_AB2
  const int rg = (lane >> 4) * 4, cl = lane & 15;
#pragma unroll
  for (int i = 0; i < 4; ++i) {
#pragma unroll
    for (int j = 0; j < 4; ++j) {
      const long row = m0 + wm * 64 + i * 16 + rg;
      const long col = n0 + wn * 64 + j * 16 + cl;
      const float bv = bias ? bias[col] : 0.0f;
#pragma unroll
      for (int r = 0; r < 4; ++r) {
        float v = acc[i][j][r] + bv;
        if (EPI == 5) {
          const long rr2 = row + r;
          u16* tgt = (rr2 < 16384) ? Cb : Cb2;
          tgt[(rr2 & 16383) * ldc + col] = f2bf(gelu_f(v));
        } else {
          long idx = (row + r) * ldc + col;
          if (EPI == 0) Cf[idx] = v;
          else if (EPI == 1) Cb[idx] = f2bf(v);
          else if (EPI == 2) Cf[idx] += v;
          else Cb[idx] = f2bf(gelu_f(v));
        }
      }
    }
  }
}

// ---------------- flash attention: full batch, 16 waves, QBLK=256, NBUF=3, 1 barrier/kt ----------------
// Q|K packed layout: qk[row][1024] = per-head [Q 0..63 | K 64..127] at col hh*128.
// Q pre-scaled by 0.125*log2e upstream -> softmax in log2 domain. Tree reductions.
// Grid 1024 blocks = (qt 4) x (hh 8) x (b 32), T1 chunked swizzle. LDS 64KB, 2 blocks/CU.
__global__ __launch_bounds__(1024)
void attn_k(const u16* __restrict__ qk, const u16* __restrict__ vt, u16* __restrict__ o)
{
  __shared__ __align__(16) u16 Ks[3][64 * 64];   // 24 KB
  __shared__ __align__(16) u16 Vts[3][64 * 64];  // 24 KB
  __shared__ __align__(16) u16 Ps[16][512];      // 16 KB: per-wave 16q x 32k
  const int tid = threadIdx.x, lane = tid & 63, wid = tid >> 6;
  int lin = blockIdx.x;
  lin = (lin & 7) * 128 + (lin >> 3);            // T1 chunked swizzle (1024 blocks)
  const int qt = lin & 3, hh = (lin >> 2) & 7, b = lin >> 5;
  const long rowbase = (long)b * 1024;
  const long vbase = (((long)b * 8 + hh) * 64) * 1024;
  const int g = lane >> 4, cl = lane & 15;
  u16* Psw = Ps[wid];
  const int Rq = wid * 16 + cl;                  // q-row in [0,256)
  const int sw2 = ((cl >> 1) & 3) << 3;          // P swizzle: XOR s on bits 3-4 of u16 idx

  // Q fragments direct from global (issued before staging)
  bf16x8 aq[2];
  {
    const u16* qp = qk + (rowbase + qt * 256 + Rq) * 1024 + hh * 128 + g * 8;
    aq[0] = *(const bf16x8*)(qp);
    aq[1] = *(const bf16x8*)(qp + 32);
  }
  // K/V stage for tile kt into buf: waves 0-7 stage K, waves 8-15 stage V (1 load/thread)
#define STAGE_KV(buf, kt_)                                                              \
  {                                                                                     \
    const int t_ = tid & 511;                                                           \
    const int row = t_ >> 3, c8s = (t_ & 7) ^ swz(row);                                 \
    if (tid < 512)                                                                      \
      gl2lds16(qk + (rowbase + (kt_) * 64 + row) * 1024 + hh * 128 + 64 + c8s * 8,      \
               Ks[buf] + t_ * 8);                                                       \
    else                                                                                \
      gl2lds16(vt + vbase + (long)row * 1024 + (kt_) * 64 + c8s * 8, Vts[buf] + t_ * 8); \
  }
  STAGE_KV(0, 0);

  float m = -3.0e38f, l = 0.f;
  f32x4 oacc[4] = {};

  for (int kt = 0; kt < 16; ++kt) {
    const int cur = kt % 3;
    if (kt < 15) {
      STAGE_KV((kt + 1) % 3, kt + 1);
      asm volatile("s_waitcnt vmcnt(1)" ::: "memory");  // aq+stage(kt) landed; stage(kt+1) in flight
    } else {
      asm volatile("s_waitcnt vmcnt(0)" ::: "memory");
    }
    __builtin_amdgcn_s_barrier();                       // all waves' stage(kt) landed
    // QK^T swapped (Q pre-scaled, log2 domain): s[j] = S^T[k = j*16 + g*4 + r][q = cl]
    f32x4 s[4] = {};
    __builtin_amdgcn_s_setprio(1);
#pragma unroll
    for (int j = 0; j < 4; ++j) {
      const int Rk = j * 16 + cl, sk = swz(Rk) << 3;
#pragma unroll
      for (int kb = 0; kb < 2; ++kb) {
        bf16x8 bk = *(const bf16x8*)(Ks[cur] + Rk * 64 + ((kb * 32 + g * 8) ^ sk));
        s[j] = mfma16(bk, aq[kb], s[j]);
      }
    }
    __builtin_amdgcn_s_setprio(0);
    // lane-local softmax: tree max over 16 values (+2-step cross-g reduce)
    float mj[4];
#pragma unroll
    for (int j = 0; j < 4; ++j)
      mj[j] = fmaxf(fmaxf(s[j][0], s[j][1]), fmaxf(s[j][2], s[j][3]));
    float mx = fmaxf(fmaxf(mj[0], mj[1]), fmaxf(mj[2], mj[3]));
    mx = fmaxf(mx, __shfl_xor(mx, 16, 64));
    mx = fmaxf(mx, __shfl_xor(mx, 32, 64));
    // defer-max (T13) in log2 domain: THR = 8*log2e (same e^8 bound)
    if (!__all(mx <= m + 11.5415603f)) {
      const float mnew = fmaxf(m, mx);
      const float al = exp2_f(m - mnew);
      m = mnew;
      l *= al;
      float alr[4];
#pragma unroll
      for (int r = 0; r < 4; ++r) alr[r] = __shfl(al, (lane & 48) | (g * 4 + r), 64);
#pragma unroll
      for (int cb = 0; cb < 4; ++cb) {
        f32x4 t = oacc[cb];
        t[0] *= alr[0]; t[1] *= alr[1]; t[2] *= alr[2]; t[3] *= alr[3];
        oacc[cb] = t;
      }
    }
    float p[4][4], tj[4];
#pragma unroll
    for (int j = 0; j < 4; ++j) {
#pragma unroll
      for (int r = 0; r < 4; ++r)
        p[j][r] = exp2_f(s[j][r] - m);
      tj[j] = (p[j][0] + p[j][1]) + (p[j][2] + p[j][3]);
    }
    float ts = (tj[0] + tj[1]) + (tj[2] + tj[3]);
    ts += __shfl_xor(ts, 16, 64);
    ts += __shfl_xor(ts, 32, 64);
    l += ts;
    // PV in two kb rounds through the compact per-wave P buffer
#pragma unroll
    for (int kb = 0; kb < 2; ++kb) {
#pragma unroll
      for (int jj = 0; jj < 2; ++jj) {
        us4 pk;
        pk[0] = f2bf(p[2 * kb + jj][0]); pk[1] = f2bf(p[2 * kb + jj][1]);
        pk[2] = f2bf(p[2 * kb + jj][2]); pk[3] = f2bf(p[2 * kb + jj][3]);
        *(us4*)(&Psw[cl * 32 + ((jj * 16 + g * 4) ^ sw2)]) = pk;
      }
      asm volatile("s_waitcnt lgkmcnt(0)" ::: "memory");
      bf16x8 pa = *(const bf16x8*)(&Psw[cl * 32 + ((g * 8) ^ sw2)]);
      __builtin_amdgcn_s_setprio(1);
#pragma unroll
      for (int cb = 0; cb < 4; ++cb) {
        const int ch = cb * 16 + cl;
        bf16x8 vb = *(const bf16x8*)(Vts[cur] + ch * 64 + ((kb * 32 + g * 8) ^ (swz(ch) << 3)));
        oacc[cb] = mfma16(pa, vb, oacc[cb]);
      }
      __builtin_amdgcn_s_setprio(0);
    }
    // no post-compute barrier: NBUF=3 ordering proof in header comment
  }
#undef STAGE_KV
  float lr[4];
#pragma unroll
  for (int r = 0; r < 4; ++r) lr[r] = __shfl(l, (lane & 48) | (g * 4 + r), 64);
#pragma unroll
  for (int cb = 0; cb < 4; ++cb)
#pragma unroll
    for (int r = 0; r < 4; ++r) {
      long row = rowbase + qt * 256 + wid * 16 + g * 4 + r;
      o[row * 512 + hh * 64 + cb * 16 + cl] = f2bf(oacc[cb][r] / lr[r]);
    }
}

// ---------------- LayerNorm, one wave per 512-row. MODE 0: f32->f32, 1: f32->bf16
template <int MODE>
__global__ __launch_bounds__(256)
void ln_k(const float* __restrict__ in_, const float* __restrict__ gg,
          const float* __restrict__ bb, void* __restrict__ out_)
{
  const long row = (long)blockIdx.x * 4 + (threadIdx.x >> 6);
  const int lane = threadIdx.x & 63;
  float x[8];
  const float* p = in_ + row * 512 + lane * 8;
  *(float4*)(x) = *(const float4*)(p);
  *(float4*)(x + 4) = *(const float4*)(p + 4);
  float s = 0.f;
#pragma unroll
  for (int j = 0; j < 8; ++j) s += x[j];
#pragma unroll
  for (int off = 1; off < 64; off <<= 1) s += __shfl_xor(s, off, 64);
  const float mean = s * (1.0f / 512.0f);
  float vs = 0.f;
#pragma unroll
  for (int j = 0; j < 8; ++j) { float d = x[j] - mean; vs += d * d; }
#pragma unroll
  for (int off = 1; off < 64; off <<= 1) vs += __shfl_xor(vs, off, 64);
  const float rstd = rsqrtf(vs * (1.0f / 512.0f) + 1e-5f);
  if (MODE == 0) {
    float y[8];
#pragma unroll
    for (int j = 0; j < 8; ++j)
      y[j] = (x[j] - mean) * rstd * gg[lane * 8 + j] + bb[lane * 8 + j];
    float* q = (float*)out_ + row * 512 + lane * 8;
    *(float4*)(q) = *(const float4*)(y);
    *(float4*)(q + 4) = *(const float4*)(y + 4);
  } else {
    us8 ov;
#pragma unroll
    for (int j = 0; j < 8; ++j)
      ov[j] = f2bf((x[j] - mean) * rstd * gg[lane * 8 + j] + bb[lane * 8 + j]);
    *(us8*)((u16*)out_ + row * 512 + lane * 8) = ov;
  }
}

// ---------------- fused LN2 + next-layer weight transpose ----------------
// blocks [0,8192): LN (f32 hf -> bf16 hn); blocks [8192, 8192+3072): trL for layer l+1
// into the weight-buffer set NOT read by the current layer (double-buffered).
__global__ __launch_bounds__(256)
void ln2trL_k(const float* __restrict__ in_, const float* __restrict__ gg,
              const float* __restrict__ bb, u16* __restrict__ out_,
              const float* __restrict__ qkv_w, const float* __restrict__ pw,
              const float* __restrict__ fcw, const float* __restrict__ fcpw,
              u16* __restrict__ o_qkv, u16* __restrict__ o_pw,
              u16* __restrict__ o_fc, u16* __restrict__ o_fcp)
{
  __shared__ u16 tile[32][33];
  if (blockIdx.x < 8192) {
    const long row = (long)blockIdx.x * 4 + (threadIdx.x >> 6);
    const int lane = threadIdx.x & 63;
    float x[8];
    const float* p = in_ + row * 512 + lane * 8;
    *(float4*)(x) = *(const float4*)(p);
    *(float4*)(x + 4) = *(const float4*)(p + 4);
    float s = 0.f;
#pragma unroll
    for (int j = 0; j < 8; ++j) s += x[j];
#pragma unroll
    for (int off = 1; off < 64; off <<= 1) s += __shfl_xor(s, off, 64);
    const float mean = s * (1.0f / 512.0f);
    float vs = 0.f;
#pragma unroll
    for (int j = 0; j < 8; ++j) { float d = x[j] - mean; vs += d * d; }
#pragma unroll
    for (int off = 1; off < 64; off <<= 1) vs += __shfl_xor(vs, off, 64);
    const float rstd = rsqrtf(vs * (1.0f / 512.0f) + 1e-5f);
    us8 ov;
#pragma unroll
    for (int j = 0; j < 8; ++j)
      ov[j] = f2bf((x[j] - mean) * rstd * gg[lane * 8 + j] + bb[lane * 8 + j]);
    *(us8*)(out_ + row * 512 + lane * 8) = ov;
    return;
  }
  int bid = (int)blockIdx.x - 8192;
  const float* src; u16* dst; int R, C, bx, by;
  if (bid < 768)       { src = qkv_w; dst = o_qkv; R = 512;  C = 1536; bx = bid % 48; by = bid / 48; }
  else if (bid < 1024) { bid -= 768;  src = pw;   dst = o_pw;  R = 512;  C = 512;  bx = bid % 16; by = bid / 16; }
  else if (bid < 2048) { bid -= 1024; src = fcw;  dst = o_fc;  R = 512;  C = 2048; bx = bid % 64; by = bid / 64; }
  else                 { bid -= 2048; src = fcpw; dst = o_fcp; R = 2048; C = 512;  bx = bid % 16; by = bid / 16; }
  const int r0 = by * 32, c0 = bx * 32;
  const int tx = threadIdx.x & 31, ty = threadIdx.x >> 5;
  for (int rr = ty; rr < 32; rr += 8) tile[rr][tx] = f2bf(src[(long)(r0 + rr) * C + c0 + tx]);
  __syncthreads();
  for (int rr = ty; rr < 32; rr += 8) dst[(long)(c0 + rr) * R + r0 + tx] = tile[tx][rr];
}

// ---------------- fused input embed + ln_pre: one block per (b,t) row ----------------
__global__ __launch_bounds__(256)
void embed_ln_k(const float* __restrict__ x, const float* __restrict__ par,
                const float* __restrict__ E, const float* __restrict__ w_in,
                const float* __restrict__ b_in, const float* __restrict__ gg,
                const float* __restrict__ bb, float* __restrict__ h)
{
  __shared__ float red[8];
  const long bt = blockIdx.x;
  const int b = (int)(bt >> 10), t = (int)(bt & 1023);
  const int tid = threadIdx.x, lane = tid & 63, wid = tid >> 6;
  float xs[9];
#pragma unroll
  for (int c = 0; c < 3; ++c) xs[c] = x[((long)b * 3 + c) * 1024 + t];
#pragma unroll
  for (int c = 0; c < 6; ++c) xs[3 + c] = par[((long)b * 6 + c) * 1024 + t];
  float a[2];
#pragma unroll
  for (int ii = 0; ii < 2; ++ii) {
    const int w = tid + ii * 256;
    float v = E[(long)t * 512 + w] + b_in[w];
#pragma unroll
    for (int c = 0; c < 9; ++c) v += xs[c] * w_in[c * 512 + w];
    a[ii] = v;
  }
  float s = a[0] + a[1];
#pragma unroll
  for (int off = 1; off < 64; off <<= 1) s += __shfl_xor(s, off, 64);
  if (lane == 0) red[wid] = s;
  __syncthreads();
  const float mean = (red[0] + red[1] + red[2] + red[3]) * (1.0f / 512.0f);
  float d0 = a[0] - mean, d1 = a[1] - mean;
  float vs = d0 * d0 + d1 * d1;
#pragma unroll
  for (int off = 1; off < 64; off <<= 1) vs += __shfl_xor(vs, off, 64);
  if (lane == 0) red[4 + wid] = vs;
  __syncthreads();
  const float rstd = rsqrtf((red[4] + red[5] + red[6] + red[7]) * (1.0f / 512.0f) + 1e-5f);
#pragma unroll
  for (int ii = 0; ii < 2; ++ii) {
    const int w = tid + ii * 256;
    h[bt * 512 + w] = (a[ii] - mean) * rstd * gg[w] + bb[w];
  }
}

// ---------------- fp32 -> bf16 transpose [R,C] -> [C,R] (generic) ----------------
__global__ __launch_bounds__(256)
void tr_k(const float* __restrict__ in, u16* __restrict__ out, int R, int C)
{
  __shared__ u16 tile[32][33];
  const int r0 = blockIdx.y * 32, c0 = blockIdx.x * 32;
  const int tx = threadIdx.x & 31, ty = threadIdx.x >> 5;
  for (int rr = ty; rr < 32; rr += 8) tile[rr][tx] = f2bf(in[(long)(r0 + rr) * C + c0 + tx]);
  __syncthreads();
  for (int rr = ty; rr < 32; rr += 8) out[(long)(c0 + rr) * R + r0 + tx] = tile[tx][rr];
}

// ---------------- fused per-layer weight transposes (qkv, pw, fc, fcp) ----------------
__global__ __launch_bounds__(256)
void trL_k(const float* __restrict__ qkv_w, const float* __restrict__ pw,
           const float* __restrict__ fcw, const float* __restrict__ fcpw,
           u16* __restrict__ o_qkv, u16* __restrict__ o_pw,
           u16* __restrict__ o_fc, u16* __restrict__ o_fcp)
{
  __shared__ u16 tile[32][33];
  int bid = blockIdx.x;
  const float* src; u16* dst; int R, C, bx, by;
  if (bid < 768)       { src = qkv_w; dst = o_qkv; R = 512;  C = 1536; bx = bid % 48; by = bid / 48; }
  else if (bid < 1024) { bid -= 768;  src = pw;   dst = o_pw;  R = 512;  C = 512;  bx = bid % 16; by = bid / 16; }
  else if (bid < 2048) { bid -= 1024; src = fcw;  dst = o_fc;  R = 512;  C = 2048; bx = bid % 64; by = bid / 64; }
  else                 { bid -= 2048; src = fcpw; dst = o_fcp; R = 2048; C = 512;  bx = bid % 16; by = bid / 16; }
  const int r0 = by * 32, c0 = bx * 32;
  const int tx = threadIdx.x & 31, ty = threadIdx.x >> 5;
  for (int rr = ty; rr < 32; rr += 8) tile[rr][tx] = f2bf(src[(long)(r0 + rr) * C + c0 + tx]);
  __syncthreads();
  for (int rr = ty; rr < 32; rr += 8) dst[(long)(c0 + rr) * R + r0 + tx] = tile[tx][rr];
}

// ---------------- fp32 -> bf16 cast ----------------
__global__ __launch_bounds__(256)
void cast_k(const float* __restrict__ in, u16* __restrict__ out, long n)
{
  long i = ((long)blockIdx.x * 256 + threadIdx.x) * 4;
  if (i + 3 < n) {
    float4 v = *(const float4*)(in + i);
    out[i] = f2bf(v.x); out[i + 1] = f2bf(v.y); out[i + 2] = f2bf(v.z); out[i + 3] = f2bf(v.w);
  }
}

// ---------------- masked max-pool, two stages ----------------
__global__ __launch_bounds__(256)
void pool1_k(const float* __restrict__ hm, const float* __restrict__ mask, float* __restrict__ part)
{
  const int c = blockIdx.x, b = blockIdx.y;
  const int t0 = c * 128;
  const int w0 = threadIdx.x, w1 = threadIdx.x + 256;
  float m0 = -3.0e38f, m1 = -3.0e38f;
  for (int t = 0; t < 128; ++t) {
    const float mv = mask[b * 1024 + t0 + t];
    const float neg = (1.0f - mv) * (-100000.0f);
    const float* row = hm + ((long)b * 1024 + t0 + t) * 512;
    m0 = fmaxf(m0, row[w0] * mv + neg);
    m1 = fmaxf(m1, row[w1] * mv + neg);
  }
  part[((long)b * 8 + c) * 512 + w0] = m0;
  part[((long)b * 8 + c) * 512 + w1] = m1;
}
__global__ __launch_bounds__(256)
void pool2_k(const float* __restrict__ part, float* __restrict__ pooled)
{
  const int b = blockIdx.y;
  const int w = blockIdx.x * 256 + threadIdx.x;
  float m = -3.0e38f;
#pragma unroll
  for (int c = 0; c < 8; ++c) m = fmaxf(m, part[((long)b * 8 + c) * 512 + w]);
  pooled[b * 512 + w] = m;
}

// ---------------- masked transpose to output h [B,512,T] fp32 ----------------
__global__ __launch_bounds__(256)
void tout_k(const float* __restrict__ hm, const float* __restrict__ mask, float* __restrict__ outh)
{
  __shared__ float tile[64][65];
  const int t0 = blockIdx.x * 64, w0 = blockIdx.y * 64, b = blockIdx.z;
  const int tx = threadIdx.x & 63, ty = threadIdx.x >> 6;
  for (int i = ty; i < 64; i += 4)
    tile[i][tx] = hm[((long)b * 1024 + t0 + i) * 512 + w0 + tx];
  __syncthreads();
  const float mv = mask[b * 1024 + t0 + tx];
  for (int i = ty; i < 64; i += 4)
    outh[((long)b * 512 + w0 + i) * 1024 + t0 + tx] = tile[tx][i] * mv;
}

// ---------------- aggregator matmuls: split-K partials + combine ----------------
__global__ __launch_bounds__(256)
void agg1p_k(const float* __restrict__ pooled, const float* __restrict__ wf,
             float* __restrict__ part)
{
  const int b = blockIdx.z, kc = blockIdx.y;
  const int n = blockIdx.x * 256 + threadIdx.x;
  float acc = 0.f;
  const int k0 = kc * 64;
#pragma unroll 8
  for (int k = 0; k < 64; ++k) acc += pooled[b * 512 + k0 + k] * wf[(long)(k0 + k) * 2048 + n];
  part[((long)b * 8 + kc) * 2048 + n] = acc;
}
__global__ __launch_bounds__(256)
void agg1c_k(const float* __restrict__ part, const float* __restrict__ bf_,
             float* __restrict__ z1)
{
  const int b = blockIdx.y;
  const int n = blockIdx.x * 256 + threadIdx.x;
  float acc = 0.f;
#pragma unroll
  for (int c = 0; c < 8; ++c) acc += part[((long)b * 8 + c) * 2048 + n];
  z1[(long)b * 2048 + n] = gelu_f(acc + bf_[n]);
}
__global__ __launch_bounds__(256)
void agg2p_k(const float* __restrict__ z1, const float* __restrict__ wp,
             float* __restrict__ part)
{
  const int b = blockIdx.z, kc = blockIdx.y;
  const int n = blockIdx.x * 256 + threadIdx.x;
  float acc = 0.f;
  const int k0 = kc * 256;
#pragma unroll 8
  for (int k = 0; k < 256; ++k) acc += z1[(long)b * 2048 + k0 + k] * wp[(long)(k0 + k) * 512 + n];
  part[((long)b * 8 + kc) * 512 + n] = acc;
}
__global__ __launch_bounds__(256)
void agg2c_k(const float* __restrict__ part, const float* __restrict__ bp,
             float* __restrict__ zo)
{
  const int b = blockIdx.y;
  const int n = blockIdx.x * 256 + threadIdx.x;
  float acc = 0.f;
#pragma unroll
  for (int c = 0; c < 8; ++c) acc += part[((long)b * 8 + c) * 512 + n];
  zo[b * 512 + n] = acc + bp[n];
}

extern "C" void kernel_launch(void* const* d_in, const int* in_sizes, int n_in,
                              void* d_out, int out_size, void* d_ws, size_t ws_size,
                              hipStream_t stream)
{
  (void)in_sizes; (void)n_in; (void)out_size; (void)ws_size;
  const float* x        = (const float*)d_in[0];
  const float* params   = (const float*)d_in[1];
  const float* mask     = (const float*)d_in[2];
  const float* class_emb= (const float*)d_in[3];
  const float* w_in     = (const float*)d_in[4];
  const float* b_in     = (const float*)d_in[5];
  const float* ln_pre_g = (const float*)d_in[6];
  const float* ln_pre_b = (const float*)d_in[7];
  const float* qkv_w    = (const float*)d_in[8];
  const float* qkv_b    = (const float*)d_in[9];
  const float* attn_pw  = (const float*)d_in[10];
  const float* attn_pb  = (const float*)d_in[11];
  const float* ln1_g    = (const float*)d_in[12];
  const float* ln1_b    = (const float*)d_in[13];
  const float* fc_w     = (const float*)d_in[14];
  const float* fc_b     = (const float*)d_in[15];
  const float* fcp_w    = (const float*)d_in[16];
  const float* fcp_b    = (const float*)d_in[17];
  const float* ln2_g    = (const float*)d_in[18];
  const float* ln2_b    = (const float*)d_in[19];
  const float* ln_post_g= (const float*)d_in[20];
  const float* ln_post_b= (const float*)d_in[21];
  const float* w_out    = (const float*)d_in[22];
  const float* b_out    = (const float*)d_in[23];
  const float* agg_fc_w = (const float*)d_in[24];
  const float* agg_fc_b = (const float*)d_in[25];
  const float* agg_pw   = (const float*)d_in[26];
  const float* agg_pb   = (const float*)d_in[27];

  float* out_f = (float*)d_out;          // z: [0, 16384)
  float* out_h = out_f + 16384;          // h: 64 MiB fp32 region
  u16* sc = (u16*)out_h;                 // bf16 scratch: Q|K [32768x1024] or FF-mid rows [0,16K)

  // ---- workspace layout (~181 MiB) ----
  char* ws = (char*)d_ws;
  float* hf = (float*)ws;       ws += (size_t)32768 * 512 * 4;
  u16* hn = (u16*)ws;           ws += (size_t)32768 * 512 * 2;
  float* E = (float*)ws;        ws += (size_t)1024 * 512 * 4;
  u16* ce_b = (u16*)ws;         ws += (size_t)1024 * 1024 * 2;
  u16* wt_qkv = (u16*)ws;       ws += (size_t)2 * 1536 * 512 * 2;   // double-buffered
  u16* wt_pw  = (u16*)ws;       ws += (size_t)2 * 512 * 512 * 2;
  u16* wt_fc  = (u16*)ws;       ws += (size_t)2 * 2048 * 512 * 2;
  u16* wt_fcp = (u16*)ws;       ws += (size_t)2 * 512 * 2048 * 2;
  u16* w_in_t = (u16*)ws;       ws += (size_t)512 * 1024 * 2;
  u16* w_out_t= (u16*)ws;       ws += (size_t)512 * 512 * 2;
  float* pooled = (float*)ws;   ws += (size_t)32 * 512 * 4;
  float* z1     = (float*)ws;   ws += (size_t)32 * 2048 * 4;
  float* part   = (float*)ws;   ws += (size_t)32 * 8 * 512 * 4;
  float* apart1 = (float*)ws;   ws += (size_t)32 * 8 * 2048 * 4;
  float* apart2 = (float*)ws;   ws += (size_t)32 * 8 * 512 * 4;
  u16* buf2     = (u16*)ws;     ws += (size_t)16384 * 2048 * 2;     // 64 MiB: FF-mid rows [16K,32K)
  u16* vt = buf2;               // V^T full batch (32 MiB) aliases buf2 (time-disjoint)

  const size_t SQ = (size_t)1536 * 512, SP = (size_t)512 * 512;
  const size_t SF = (size_t)2048 * 512, SG = (size_t)512 * 2048;

  // one-time converts + class-emb projection + fused embed+ln_pre
  cast_k<<<1024, 256, 0, stream>>>(class_emb, ce_b, 1024 * 1024);
  tr_k<<<dim3(16, 32), 256, 0, stream>>>(w_in + 9 * 512, w_in_t, 1024, 512);
  tr_k<<<dim3(16, 16), 256, 0, stream>>>(w_out, w_out_t, 512, 512);
  gemm_bt<0><<<dim3(4, 4), 512, 0, stream>>>(ce_b, w_in_t, nullptr, E, nullptr, nullptr,
                                             1024, 1024, 1024, 512);
  embed_ln_k<<<32768, 256, 0, stream>>>(x, params, E, w_in, b_in, ln_pre_g, ln_pre_b, hf);
  // layer-0 weight transpose into set 0
  trL_k<<<3072, 256, 0, stream>>>(qkv_w, attn_pw, fc_w, fcp_w,
                                  wt_qkv, wt_pw, wt_fc, wt_fcp);

  for (int l = 0; l < 12; ++l) {
    const size_t cs = (size_t)(l & 1), ns = (size_t)((l + 1) & 1);

    // LN1 full batch -> hn (bf16)
    ln_k<1><<<8192, 256, 0, stream>>>(hf, ln1_g + l * 512, ln1_b + l * 512, hn);
    // QKV full batch (Q|K packed -> sc, V^T -> vt) + attention full batch (out -> hn)
    gemm_bt<4><<<dim3(12, 128), 512, 0, stream>>>(hn, wt_qkv + cs * SQ, qkv_b + l * 1536,
                                                  nullptr, sc, vt, 512, 512, 512, 1024);
    attn_k<<<1024, 1024, 0, stream>>>(sc, vt, hn);
    // attn projection full batch: h += hn @ pw^T + b
    gemm_bt<2><<<dim3(4, 128), 512, 0, stream>>>(hn, wt_pw + cs * SP, attn_pb + l * 512,
                                                 hf, nullptr, nullptr, 512, 512, 512, 512);
    // LN2 full batch -> hn, fused with next layer's weight transpose (into set ns)
    if (l < 11) {
      ln2trL_k<<<11264, 256, 0, stream>>>(hf, ln2_g + l * 512, ln2_b + l * 512, hn,
                                          qkv_w + (size_t)(l + 1) * 512 * 1536,
                                          attn_pw + (size_t)(l + 1) * 512 * 512,
                                          fc_w + (size_t)(l + 1) * 512 * 2048,
                                          fcp_w + (size_t)(l + 1) * 2048 * 512,
                                          wt_qkv + ns * SQ, wt_pw + ns * SP,
                                          wt_fc + ns * SF, wt_fcp + ns * SG);
    } else {
      ln_k<1><<<8192, 256, 0, stream>>>(hf, ln2_g + l * 512, ln2_b + l * 512, hn);
    }
    // FF full batch: fc (gelu, split-write sc/buf2) then fcp (split-read, residual into hf)
    gemm_bt2<5><<<dim3(8, 128), 1024, 0, stream>>>(hn, wt_fc + cs * SF, fc_b + l * 2048,
                                                   nullptr, sc, buf2, 512, 512, 512, 2048);
    gemm_bt1<2><<<dim3(4, 256), 256, 0, stream>>>(sc, buf2, wt_fcp + cs * SG, fcp_b + l * 512,
                                                  hf, nullptr, 2048, 2048, 2048, 512);
  }

  // final LN + out-proj, then pool/agg, then h output
  ln_k<1><<<8192, 256, 0, stream>>>(hf, ln_post_g, ln_post_b, hn);
  gemm_bt<0><<<dim3(4, 128), 512, 0, stream>>>(hn, w_out_t, b_out, hf, nullptr, nullptr,
                                               512, 512, 512, 512);
  pool1_k<<<dim3(8, 32), 256, 0, stream>>>(hf, mask, part);
  pool2_k<<<dim3(2, 32), 256, 0, stream>>>(part, pooled);
  agg1p_k<<<dim3(8, 8, 32), 256, 0, stream>>>(pooled, agg_fc_w, apart1);
  agg1c_k<<<dim3(8, 32), 256, 0, stream>>>(apart1, agg_fc_b, z1);
  agg2p_k<<<dim3(2, 8, 32), 256, 0, stream>>>(z1, agg_pw, apart2);
  agg2c_k<<<dim3(2, 32), 256, 0, stream>>>(apart2, agg_pb, out_f);
  tout_k<<<dim3(16, 8, 32), 256, 0, stream>>>(hf, mask, out_h);
}

// Round 28
// 5893.976 us; speedup vs baseline: 1.0574x; 1.0574x over previous
//
#include <hip/hip_runtime.h>
#include <hip/hip_bf16.h>

// PartCodeTransformer forward on MI355X (gfx950).
// I/O fp32; internal bf16 MFMA + fp32 accum/residual.
// Round 28: fcp moved from the 128x128/4-wave gemm_bt1 (~443 TF measured, r27 top-5)
// to the 256x128/8-wave gemm_bt with A2 split-read (rows >= 16384 from buf2;
// 16384 % 256 == 0 so base-select is tile-uniform). Grid 4x128 = 512 blocks, 2/CU.
// gemm_bt1 deleted. Same accumulation order -> bit-identical. All else = round 27.

typedef unsigned short u16;
typedef unsigned int u32;
typedef __attribute__((ext_vector_type(8))) short bf16x8;
typedef __attribute__((ext_vector_type(8))) unsigned short us8;
typedef __attribute__((ext_vector_type(4))) unsigned short us4;
typedef __attribute__((ext_vector_type(4))) float f32x4;

__device__ __forceinline__ float bf2f(u16 s) {
  union { u32 u; float f; } c; c.u = ((u32)s) << 16; return c.f;
}
__device__ __forceinline__ u16 f2bf(float f) {
  __hip_bfloat16 h = __float2bfloat16(f);   // hardware RNE cvt
  union { __hip_bfloat16 h; u16 u; } c; c.h = h; return c.u;
}
__device__ __forceinline__ float gelu_f(float v) {
  return 0.5f * v * (1.0f + erff(v * 0.7071067811865475f));
}
__device__ __forceinline__ void gl2lds16(const u16* g, u16* l) {
  __builtin_amdgcn_global_load_lds((const __attribute__((address_space(1))) void*)g,
                                   (__attribute__((address_space(3))) void*)l, 16, 0, 0);
}
__device__ __forceinline__ f32x4 mfma16(bf16x8 a, bf16x8 b, f32x4 c) {
  return __builtin_amdgcn_mfma_f32_16x16x32_bf16(a, b, c, 0, 0, 0);
}
__device__ __forceinline__ float exp2_f(float x) { return __builtin_amdgcn_exp2f(x); }
// chunk swizzle for 128B rows (attn K/V): permute 16B chunks within the row
__device__ __forceinline__ int swz(int row) { return (row ^ (row >> 3)) & 7; }

// ------------- A[M,K](lda) x Bt[N,K](ldb) GEMM, 256x128 tile, 8 waves, 2-phase dbuf -------------
// LDS swizzle: phys_chunk = log_chunk ^ ((row>>1)&3).
// A2: if non-null, tile rows >= 16384 of A are read from A2 (local row = row - 16384);
//     tile-uniform since 16384 % 256 == 0. Epilogue keeps global row.
// EPI: 0 f32=v ; 1 bf16=v ; 2 f32+=v ; 3 bf16=gelu(v)
// EPI 4 (qkv): Q(x0.125*log2e)/K packed -> Cb[row*1024 + hh*128 + off]; V -> Vt transposed.
template <int EPI>
__global__ __launch_bounds__(512)
void gemm_bt(const u16* __restrict__ A, const u16* __restrict__ A2,
             const u16* __restrict__ Bt,
             const float* __restrict__ bias, float* __restrict__ Cf,
             u16* __restrict__ Cb, u16* __restrict__ Vt, int K, int lda, int ldb, int ldc)
{
  __shared__ __align__(16) u16 As[2][256 * 32];   // 32 KB
  __shared__ __align__(16) u16 Bs[2][128 * 32];   // 16 KB
  const int tid = threadIdx.x;
  const int lane = tid & 63, wid = tid >> 6;
  const int wm = wid & 3, wn = wid >> 2;          // 4 M-waves x 2 N-waves
  const int nbx = gridDim.x;
  const int nwg = nbx * gridDim.y;
  int lin = blockIdx.y * nbx + blockIdx.x;
  lin = (lin & 7) * (nwg >> 3) + (lin >> 3);
  const long m0 = (long)(lin / nbx) * 256, n0 = (long)(lin % nbx) * 128;

  // A-base select (tile-uniform)
  const u16* Ab = A;
  long m0a = m0;
  if (A2 && m0 >= 16384) { Ab = A2; m0a = m0 - 16384; }

  const int c0 = tid, c1 = tid + 512;
  const int kc0 = (c0 & 3) ^ (((c0 >> 2) >> 1) & 3);
  const int kc1 = (c1 & 3) ^ (((c1 >> 2) >> 1) & 3);
  const int kcb = (tid & 3) ^ (((tid >> 2) >> 1) & 3);
  const u16* aS0 = Ab + (m0a + (c0 >> 2)) * (long)lda + kc0 * 8;
  const u16* aS1 = Ab + (m0a + (c1 >> 2)) * (long)lda + kc1 * 8;
  const u16* bS0 = Bt + (n0 + (tid >> 2)) * (long)ldb + kcb * 8;

  f32x4 acc[4][4] = {};
  const int cl4 = lane & 15;
  const int gph = ((lane >> 4) ^ ((cl4 >> 1) & 3)) * 8;
  const int aro = (wm * 64 + cl4) * 32 + gph;
  const int bro = (wn * 64 + cl4) * 32 + gph;
  const int nt = K >> 5;

#define STAGE_AB(buf, k0_)                          \
  gl2lds16(aS0 + (k0_), As[buf] + c0 * 8);          \
  gl2lds16(aS1 + (k0_), As[buf] + c1 * 8);          \
  gl2lds16(bS0 + (k0_), Bs[buf] + tid * 8);

  STAGE_AB(0, 0);
  for (int t = 0; t < nt; ++t) {
    const int cur = t & 1;
    if (t < nt - 1) {
      STAGE_AB(cur ^ 1, (t + 1) * 32);
      asm volatile("s_waitcnt vmcnt(3)" ::: "memory");
    } else {
      asm volatile("s_waitcnt vmcnt(0)" ::: "memory");
    }
    __builtin_amdgcn_s_barrier();
    bf16x8 af[4], bfr[4];
#pragma unroll
    for (int i = 0; i < 4; ++i) af[i] = *(const bf16x8*)(As[cur] + aro + i * 16 * 32);
#pragma unroll
    for (int j = 0; j < 4; ++j) bfr[j] = *(const bf16x8*)(Bs[cur] + bro + j * 16 * 32);
    __builtin_amdgcn_s_setprio(1);
#pragma unroll
    for (int i = 0; i < 4; ++i)
#pragma unroll
      for (int j = 0; j < 4; ++j)
        acc[i][j] = mfma16(af[i], bfr[j], acc[i][j]);
    __builtin_amdgcn_s_setprio(0);
    __builtin_amdgcn_s_barrier();
  }
#undef STAGE_AB
  const int rg = (lane >> 4) * 4, cl = lane & 15;
#pragma unroll
  for (int i = 0; i < 4; ++i) {
#pragma unroll
    for (int j = 0; j < 4; ++j) {
      const long row = m0 + wm * 64 + i * 16 + rg;
      const long col = n0 + wn * 64 + j * 16 + cl;
      const float bv = bias ? bias[col] : 0.0f;
      if (EPI == 4) {
        const int hh = (int)col / 192, off = (int)col - hh * 192;
        if (off < 64) {       // Q: pre-scale by 0.125*log2(e) (softmax in log2 domain)
#pragma unroll
          for (int r = 0; r < 4; ++r)
            Cb[(row + r) * ldc + hh * 128 + off] = f2bf((acc[i][j][r] + bv) * 0.1803368801111244f);
        } else if (off < 128) {  // K
#pragma unroll
          for (int r = 0; r < 4; ++r)
            Cb[(row + r) * ldc + hh * 128 + off] = f2bf(acc[i][j][r] + bv);
        } else {              // V -> transposed vt
          us4 pk;
#pragma unroll
          for (int r = 0; r < 4; ++r) pk[r] = f2bf(acc[i][j][r] + bv);
          const long bl = row >> 10, t0 = row & 1023;
          *(us4*)(Vt + (((bl * 8 + hh) * 64 + (off - 128)) << 10) + t0) = pk;
        }
      } else {
#pragma unroll
        for (int r = 0; r < 4; ++r) {
          float v = acc[i][j][r] + bv;
          long idx = (row + r) * ldc + col;
          if (EPI == 0) Cf[idx] = v;
          else if (EPI == 1) Cb[idx] = f2bf(v);
          else if (EPI == 2) Cf[idx] += v;
          else Cb[idx] = f2bf(gelu_f(v));
        }
      }
    }
  }
}

// ------------- 256x256 tile, 16 waves (1024 thr), 2-phase dbuf — for fc -------------
// EPI 3: bf16=gelu(v) -> Cb. EPI 5: gelu, rows<16384 -> Cb, rows>=16384 -> Cb2 (row-16384).
template <int EPI>
__global__ __launch_bounds__(1024)
void gemm_bt2(const u16* __restrict__ A, const u16* __restrict__ Bt,
              const float* __restrict__ bias, float* __restrict__ Cf,
              u16* __restrict__ Cb, u16* __restrict__ Cb2, int K, int lda, int ldb, int ldc)
{
  __shared__ __align__(16) u16 As[2][256 * 32];   // 32 KB
  __shared__ __align__(16) u16 Bs[2][256 * 32];   // 32 KB
  const int tid = threadIdx.x;
  const int lane = tid & 63, wid = tid >> 6;
  const int wm = wid & 3, wn = wid >> 2;          // 4x4 waves
  const int nbx = gridDim.x;
  const int nwg = nbx * gridDim.y;
  int lin = blockIdx.y * nbx + blockIdx.x;
  lin = (lin & 7) * (nwg >> 3) + (lin >> 3);
  const long m0 = (long)(lin / nbx) * 256, n0 = (long)(lin % nbx) * 256;

  const int kcA = (tid & 3) ^ (((tid >> 2) >> 1) & 3);
  const u16* aS0 = A + (m0 + (tid >> 2)) * (long)lda + kcA * 8;
  const u16* bS0 = Bt + (n0 + (tid >> 2)) * (long)ldb + kcA * 8;

  f32x4 acc[4][4] = {};
  const int cl4 = lane & 15;
  const int gph = ((lane >> 4) ^ ((cl4 >> 1) & 3)) * 8;
  const int aro = (wm * 64 + cl4) * 32 + gph;
  const int bro = (wn * 64 + cl4) * 32 + gph;
  const int nt = K >> 5;

#define STAGE_AB2(buf, k0_)                         \
  gl2lds16(aS0 + (k0_), As[buf] + tid * 8);         \
  gl2lds16(bS0 + (k0_), Bs[buf] + tid * 8);

  STAGE_AB2(0, 0);
  for (int t = 0; t < nt; ++t) {
    const int cur = t & 1;
    if (t < nt - 1) {
      STAGE_AB2(cur ^ 1, (t + 1) * 32);
      asm volatile("s_waitcnt vmcnt(2)" ::: "memory");
    } else {
      asm volatile("s_waitcnt vmcnt(0)" ::: "memory");
    }
    __builtin_amdgcn_s_barrier();
    bf16x8 af[4], bfr[4];
#pragma unroll
    for (int i = 0; i < 4; ++i) af[i] = *(const bf16x8*)(As[cur] + aro + i * 16 * 32);
#pragma unroll
    for (int j = 0; j < 4; ++j) bfr[j] = *(const bf16x8*)(Bs[cur] + bro + j * 16 * 32);
    __builtin_amdgcn_s_setprio(1);
#pragma unroll
    for (int i = 0; i < 4; ++i)
#pragma unroll
      for (int j = 0; j < 4; ++j)
        acc[i][j] = mfma16(af[i], bfr[j], acc[i][j]);
    __builtin_amdgcn_s_setprio(0);
    __builtin_amdgcn_s_barrier();
  }
#undef STAGE_AB2
  const int rg = (lane >> 4) * 4, cl = lane & 15;
#pragma unroll
  for (int i = 0; i < 4; ++i) {
#pragma unroll
    for (int j = 0; j < 4; ++j) {
      const long row = m0 + wm * 64 + i * 16 + rg;
      const long col = n0 + wn * 64 + j * 16 + cl;
      const float bv = bias ? bias[col] : 0.0f;
#pragma unroll
      for (int r = 0; r < 4; ++r) {
        float v = acc[i][j][r] + bv;
        if (EPI == 5) {
          const long rr2 = row + r;
          u16* tgt = (rr2 < 16384) ? Cb : Cb2;
          tgt[(rr2 & 16383) * ldc + col] = f2bf(gelu_f(v));
        } else {
          long idx = (row + r) * ldc + col;
          if (EPI == 0) Cf[idx] = v;
          else if (EPI == 1) Cb[idx] = f2bf(v);
          else if (EPI == 2) Cf[idx] += v;
          else Cb[idx] = f2bf(gelu_f(v));
        }
      }
    }
  }
}

// ---------------- flash attention: full batch, 16 waves, QBLK=256, NBUF=3, 1 barrier/kt ----------------
// Q|K packed layout: qk[row][1024] = per-head [Q 0..63 | K 64..127] at col hh*128.
// Q pre-scaled by 0.125*log2e upstream -> softmax in log2 domain. Tree reductions.
// Grid 1024 blocks = (qt 4) x (hh 8) x (b 32), T1 chunked swizzle. LDS 64KB, 2 blocks/CU.
__global__ __launch_bounds__(1024)
void attn_k(const u16* __restrict__ qk, const u16* __restrict__ vt, u16* __restrict__ o)
{
  __shared__ __align__(16) u16 Ks[3][64 * 64];   // 24 KB
  __shared__ __align__(16) u16 Vts[3][64 * 64];  // 24 KB
  __shared__ __align__(16) u16 Ps[16][512];      // 16 KB: per-wave 16q x 32k
  const int tid = threadIdx.x, lane = tid & 63, wid = tid >> 6;
  int lin = blockIdx.x;
  lin = (lin & 7) * 128 + (lin >> 3);            // T1 chunked swizzle (1024 blocks)
  const int qt = lin & 3, hh = (lin >> 2) & 7, b = lin >> 5;
  const long rowbase = (long)b * 1024;
  const long vbase = (((long)b * 8 + hh) * 64) * 1024;
  const int g = lane >> 4, cl = lane & 15;
  u16* Psw = Ps[wid];
  const int Rq = wid * 16 + cl;                  // q-row in [0,256)
  const int sw2 = ((cl >> 1) & 3) << 3;          // P swizzle: XOR s on bits 3-4 of u16 idx

  // Q fragments direct from global (issued before staging)
  bf16x8 aq[2];
  {
    const u16* qp = qk + (rowbase + qt * 256 + Rq) * 1024 + hh * 128 + g * 8;
    aq[0] = *(const bf16x8*)(qp);
    aq[1] = *(const bf16x8*)(qp + 32);
  }
  // K/V stage for tile kt into buf: waves 0-7 stage K, waves 8-15 stage V (1 load/thread)
#define STAGE_KV(buf, kt_)                                                              \
  {                                                                                     \
    const int t_ = tid & 511;                                                           \
    const int row = t_ >> 3, c8s = (t_ & 7) ^ swz(row);                                 \
    if (tid < 512)                                                                      \
      gl2lds16(qk + (rowbase + (kt_) * 64 + row) * 1024 + hh * 128 + 64 + c8s * 8,      \
               Ks[buf] + t_ * 8);                                                       \
    else                                                                                \
      gl2lds16(vt + vbase + (long)row * 1024 + (kt_) * 64 + c8s * 8, Vts[buf] + t_ * 8); \
  }
  STAGE_KV(0, 0);

  float m = -3.0e38f, l = 0.f;
  f32x4 oacc[4] = {};

  for (int kt = 0; kt < 16; ++kt) {
    const int cur = kt % 3;
    if (kt < 15) {
      STAGE_KV((kt + 1) % 3, kt + 1);
      asm volatile("s_waitcnt vmcnt(1)" ::: "memory");  // aq+stage(kt) landed; stage(kt+1) in flight
    } else {
      asm volatile("s_waitcnt vmcnt(0)" ::: "memory");
    }
    __builtin_amdgcn_s_barrier();                       // all waves' stage(kt) landed
    // QK^T swapped (Q pre-scaled, log2 domain): s[j] = S^T[k = j*16 + g*4 + r][q = cl]
    f32x4 s[4] = {};
    __builtin_amdgcn_s_setprio(1);
#pragma unroll
    for (int j = 0; j < 4; ++j) {
      const int Rk = j * 16 + cl, sk = swz(Rk) << 3;
#pragma unroll
      for (int kb = 0; kb < 2; ++kb) {
        bf16x8 bk = *(const bf16x8*)(Ks[cur] + Rk * 64 + ((kb * 32 + g * 8) ^ sk));
        s[j] = mfma16(bk, aq[kb], s[j]);
      }
    }
    __builtin_amdgcn_s_setprio(0);
    // lane-local softmax: tree max over 16 values (+2-step cross-g reduce)
    float mj[4];
#pragma unroll
    for (int j = 0; j < 4; ++j)
      mj[j] = fmaxf(fmaxf(s[j][0], s[j][1]), fmaxf(s[j][2], s[j][3]));
    float mx = fmaxf(fmaxf(mj[0], mj[1]), fmaxf(mj[2], mj[3]));
    mx = fmaxf(mx, __shfl_xor(mx, 16, 64));
    mx = fmaxf(mx, __shfl_xor(mx, 32, 64));
    // defer-max (T13) in log2 domain: THR = 8*log2e (same e^8 bound)
    if (!__all(mx <= m + 11.5415603f)) {
      const float mnew = fmaxf(m, mx);
      const float al = exp2_f(m - mnew);
      m = mnew;
      l *= al;
      float alr[4];
#pragma unroll
      for (int r = 0; r < 4; ++r) alr[r] = __shfl(al, (lane & 48) | (g * 4 + r), 64);
#pragma unroll
      for (int cb = 0; cb < 4; ++cb) {
        f32x4 t = oacc[cb];
        t[0] *= alr[0]; t[1] *= alr[1]; t[2] *= alr[2]; t[3] *= alr[3];
        oacc[cb] = t;
      }
    }
    float p[4][4], tj[4];
#pragma unroll
    for (int j = 0; j < 4; ++j) {
#pragma unroll
      for (int r = 0; r < 4; ++r)
        p[j][r] = exp2_f(s[j][r] - m);
      tj[j] = (p[j][0] + p[j][1]) + (p[j][2] + p[j][3]);
    }
    float ts = (tj[0] + tj[1]) + (tj[2] + tj[3]);
    ts += __shfl_xor(ts, 16, 64);
    ts += __shfl_xor(ts, 32, 64);
    l += ts;
    // PV in two kb rounds through the compact per-wave P buffer
#pragma unroll
    for (int kb = 0; kb < 2; ++kb) {
#pragma unroll
      for (int jj = 0; jj < 2; ++jj) {
        us4 pk;
        pk[0] = f2bf(p[2 * kb + jj][0]); pk[1] = f2bf(p[2 * kb + jj][1]);
        pk[2] = f2bf(p[2 * kb + jj][2]); pk[3] = f2bf(p[2 * kb + jj][3]);
        *(us4*)(&Psw[cl * 32 + ((jj * 16 + g * 4) ^ sw2)]) = pk;
      }
      asm volatile("s_waitcnt lgkmcnt(0)" ::: "memory");
      bf16x8 pa = *(const bf16x8*)(&Psw[cl * 32 + ((g * 8) ^ sw2)]);
      __builtin_amdgcn_s_setprio(1);
#pragma unroll
      for (int cb = 0; cb < 4; ++cb) {
        const int ch = cb * 16 + cl;
        bf16x8 vb = *(const bf16x8*)(Vts[cur] + ch * 64 + ((kb * 32 + g * 8) ^ (swz(ch) << 3)));
        oacc[cb] = mfma16(pa, vb, oacc[cb]);
      }
      __builtin_amdgcn_s_setprio(0);
    }
    // no post-compute barrier: NBUF=3 ordering proof in header comment
  }
#undef STAGE_KV
  float lr[4];
#pragma unroll
  for (int r = 0; r < 4; ++r) lr[r] = __shfl(l, (lane & 48) | (g * 4 + r), 64);
#pragma unroll
  for (int cb = 0; cb < 4; ++cb)
#pragma unroll
    for (int r = 0; r < 4; ++r) {
      long row = rowbase + qt * 256 + wid * 16 + g * 4 + r;
      o[row * 512 + hh * 64 + cb * 16 + cl] = f2bf(oacc[cb][r] / lr[r]);
    }
}

// ---------------- LayerNorm, one wave per 512-row. MODE 0: f32->f32, 1: f32->bf16
template <int MODE>
__global__ __launch_bounds__(256)
void ln_k(const float* __restrict__ in_, const float* __restrict__ gg,
          const float* __restrict__ bb, void* __restrict__ out_)
{
  const long row = (long)blockIdx.x * 4 + (threadIdx.x >> 6);
  const int lane = threadIdx.x & 63;
  float x[8];
  const float* p = in_ + row * 512 + lane * 8;
  *(float4*)(x) = *(const float4*)(p);
  *(float4*)(x + 4) = *(const float4*)(p + 4);
  float s = 0.f;
#pragma unroll
  for (int j = 0; j < 8; ++j) s += x[j];
#pragma unroll
  for (int off = 1; off < 64; off <<= 1) s += __shfl_xor(s, off, 64);
  const float mean = s * (1.0f / 512.0f);
  float vs = 0.f;
#pragma unroll
  for (int j = 0; j < 8; ++j) { float d = x[j] - mean; vs += d * d; }
#pragma unroll
  for (int off = 1; off < 64; off <<= 1) vs += __shfl_xor(vs, off, 64);
  const float rstd = rsqrtf(vs * (1.0f / 512.0f) + 1e-5f);
  if (MODE == 0) {
    float y[8];
#pragma unroll
    for (int j = 0; j < 8; ++j)
      y[j] = (x[j] - mean) * rstd * gg[lane * 8 + j] + bb[lane * 8 + j];
    float* q = (float*)out_ + row * 512 + lane * 8;
    *(float4*)(q) = *(const float4*)(y);
    *(float4*)(q + 4) = *(const float4*)(y + 4);
  } else {
    us8 ov;
#pragma unroll
    for (int j = 0; j < 8; ++j)
      ov[j] = f2bf((x[j] - mean) * rstd * gg[lane * 8 + j] + bb[lane * 8 + j]);
    *(us8*)((u16*)out_ + row * 512 + lane * 8) = ov;
  }
}

// ---------------- fused LN2 + next-layer weight transpose ----------------
// blocks [0,8192): LN (f32 hf -> bf16 hn); blocks [8192, 8192+3072): trL for layer l+1
// into the weight-buffer set NOT read by the current layer (double-buffered).
__global__ __launch_bounds__(256)
void ln2trL_k(const float* __restrict__ in_, const float* __restrict__ gg,
              const float* __restrict__ bb, u16* __restrict__ out_,
              const float* __restrict__ qkv_w, const float* __restrict__ pw,
              const float* __restrict__ fcw, const float* __restrict__ fcpw,
              u16* __restrict__ o_qkv, u16* __restrict__ o_pw,
              u16* __restrict__ o_fc, u16* __restrict__ o_fcp)
{
  __shared__ u16 tile[32][33];
  if (blockIdx.x < 8192) {
    const long row = (long)blockIdx.x * 4 + (threadIdx.x >> 6);
    const int lane = threadIdx.x & 63;
    float x[8];
    const float* p = in_ + row * 512 + lane * 8;
    *(float4*)(x) = *(const float4*)(p);
    *(float4*)(x + 4) = *(const float4*)(p + 4);
    float s = 0.f;
#pragma unroll
    for (int j = 0; j < 8; ++j) s += x[j];
#pragma unroll
    for (int off = 1; off < 64; off <<= 1) s += __shfl_xor(s, off, 64);
    const float mean = s * (1.0f / 512.0f);
    float vs = 0.f;
#pragma unroll
    for (int j = 0; j < 8; ++j) { float d = x[j] - mean; vs += d * d; }
#pragma unroll
    for (int off = 1; off < 64; off <<= 1) vs += __shfl_xor(vs, off, 64);
    const float rstd = rsqrtf(vs * (1.0f / 512.0f) + 1e-5f);
    us8 ov;
#pragma unroll
    for (int j = 0; j < 8; ++j)
      ov[j] = f2bf((x[j] - mean) * rstd * gg[lane * 8 + j] + bb[lane * 8 + j]);
    *(us8*)(out_ + row * 512 + lane * 8) = ov;
    return;
  }
  int bid = (int)blockIdx.x - 8192;
  const float* src; u16* dst; int R, C, bx, by;
  if (bid < 768)       { src = qkv_w; dst = o_qkv; R = 512;  C = 1536; bx = bid % 48; by = bid / 48; }
  else if (bid < 1024) { bid -= 768;  src = pw;   dst = o_pw;  R = 512;  C = 512;  bx = bid % 16; by = bid / 16; }
  else if (bid < 2048) { bid -= 1024; src = fcw;  dst = o_fc;  R = 512;  C = 2048; bx = bid % 64; by = bid / 64; }
  else                 { bid -= 2048; src = fcpw; dst = o_fcp; R = 2048; C = 512;  bx = bid % 16; by = bid / 16; }
  const int r0 = by * 32, c0 = bx * 32;
  const int tx = threadIdx.x & 31, ty = threadIdx.x >> 5;
  for (int rr = ty; rr < 32; rr += 8) tile[rr][tx] = f2bf(src[(long)(r0 + rr) * C + c0 + tx]);
  __syncthreads();
  for (int rr = ty; rr < 32; rr += 8) dst[(long)(c0 + rr) * R + r0 + tx] = tile[tx][rr];
}

// ---------------- fused input embed + ln_pre: one block per (b,t) row ----------------
__global__ __launch_bounds__(256)
void embed_ln_k(const float* __restrict__ x, const float* __restrict__ par,
                const float* __restrict__ E, const float* __restrict__ w_in,
                const float* __restrict__ b_in, const float* __restrict__ gg,
                const float* __restrict__ bb, float* __restrict__ h)
{
  __shared__ float red[8];
  const long bt = blockIdx.x;
  const int b = (int)(bt >> 10), t = (int)(bt & 1023);
  const int tid = threadIdx.x, lane = tid & 63, wid = tid >> 6;
  float xs[9];
#pragma unroll
  for (int c = 0; c < 3; ++c) xs[c] = x[((long)b * 3 + c) * 1024 + t];
#pragma unroll
  for (int c = 0; c < 6; ++c) xs[3 + c] = par[((long)b * 6 + c) * 1024 + t];
  float a[2];
#pragma unroll
  for (int ii = 0; ii < 2; ++ii) {
    const int w = tid + ii * 256;
    float v = E[(long)t * 512 + w] + b_in[w];
#pragma unroll
    for (int c = 0; c < 9; ++c) v += xs[c] * w_in[c * 512 + w];
    a[ii] = v;
  }
  float s = a[0] + a[1];
#pragma unroll
  for (int off = 1; off < 64; off <<= 1) s += __shfl_xor(s, off, 64);
  if (lane == 0) red[wid] = s;
  __syncthreads();
  const float mean = (red[0] + red[1] + red[2] + red[3]) * (1.0f / 512.0f);
  float d0 = a[0] - mean, d1 = a[1] - mean;
  float vs = d0 * d0 + d1 * d1;
#pragma unroll
  for (int off = 1; off < 64; off <<= 1) vs += __shfl_xor(vs, off, 64);
  if (lane == 0) red[4 + wid] = vs;
  __syncthreads();
  const float rstd = rsqrtf((red[4] + red[5] + red[6] + red[7]) * (1.0f / 512.0f) + 1e-5f);
#pragma unroll
  for (int ii = 0; ii < 2; ++ii) {
    const int w = tid + ii * 256;
    h[bt * 512 + w] = (a[ii] - mean) * rstd * gg[w] + bb[w];
  }
}

// ---------------- fp32 -> bf16 transpose [R,C] -> [C,R] (generic) ----------------
__global__ __launch_bounds__(256)
void tr_k(const float* __restrict__ in, u16* __restrict__ out, int R, int C)
{
  __shared__ u16 tile[32][33];
  const int r0 = blockIdx.y * 32, c0 = blockIdx.x * 32;
  const int tx = threadIdx.x & 31, ty = threadIdx.x >> 5;
  for (int rr = ty; rr < 32; rr += 8) tile[rr][tx] = f2bf(in[(long)(r0 + rr) * C + c0 + tx]);
  __syncthreads();
  for (int rr = ty; rr < 32; rr += 8) out[(long)(c0 + rr) * R + r0 + tx] = tile[tx][rr];
}

// ---------------- fused per-layer weight transposes (qkv, pw, fc, fcp) ----------------
__global__ __launch_bounds__(256)
void trL_k(const float* __restrict__ qkv_w, const float* __restrict__ pw,
           const float* __restrict__ fcw, const float* __restrict__ fcpw,
           u16* __restrict__ o_qkv, u16* __restrict__ o_pw,
           u16* __restrict__ o_fc, u16* __restrict__ o_fcp)
{
  __shared__ u16 tile[32][33];
  int bid = blockIdx.x;
  const float* src; u16* dst; int R, C, bx, by;
  if (bid < 768)       { src = qkv_w; dst = o_qkv; R = 512;  C = 1536; bx = bid % 48; by = bid / 48; }
  else if (bid < 1024) { bid -= 768;  src = pw;   dst = o_pw;  R = 512;  C = 512;  bx = bid % 16; by = bid / 16; }
  else if (bid < 2048) { bid -= 1024; src = fcw;  dst = o_fc;  R = 512;  C = 2048; bx = bid % 64; by = bid / 64; }
  else                 { bid -= 2048; src = fcpw; dst = o_fcp; R = 2048; C = 512;  bx = bid % 16; by = bid / 16; }
  const int r0 = by * 32, c0 = bx * 32;
  const int tx = threadIdx.x & 31, ty = threadIdx.x >> 5;
  for (int rr = ty; rr < 32; rr += 8) tile[rr][tx] = f2bf(src[(long)(r0 + rr) * C + c0 + tx]);
  __syncthreads();
  for (int rr = ty; rr < 32; rr += 8) dst[(long)(c0 + rr) * R + r0 + tx] = tile[tx][rr];
}

// ---------------- fp32 -> bf16 cast ----------------
__global__ __launch_bounds__(256)
void cast_k(const float* __restrict__ in, u16* __restrict__ out, long n)
{
  long i = ((long)blockIdx.x * 256 + threadIdx.x) * 4;
  if (i + 3 < n) {
    float4 v = *(const float4*)(in + i);
    out[i] = f2bf(v.x); out[i + 1] = f2bf(v.y); out[i + 2] = f2bf(v.z); out[i + 3] = f2bf(v.w);
  }
}

// ---------------- masked max-pool, two stages ----------------
__global__ __launch_bounds__(256)
void pool1_k(const float* __restrict__ hm, const float* __restrict__ mask, float* __restrict__ part)
{
  const int c = blockIdx.x, b = blockIdx.y;
  const int t0 = c * 128;
  const int w0 = threadIdx.x, w1 = threadIdx.x + 256;
  float m0 = -3.0e38f, m1 = -3.0e38f;
  for (int t = 0; t < 128; ++t) {
    const float mv = mask[b * 1024 + t0 + t];
    const float neg = (1.0f - mv) * (-100000.0f);
    const float* row = hm + ((long)b * 1024 + t0 + t) * 512;
    m0 = fmaxf(m0, row[w0] * mv + neg);
    m1 = fmaxf(m1, row[w1] * mv + neg);
  }
  part[((long)b * 8 + c) * 512 + w0] = m0;
  part[((long)b * 8 + c) * 512 + w1] = m1;
}
__global__ __launch_bounds__(256)
void pool2_k(const float* __restrict__ part, float* __restrict__ pooled)
{
  const int b = blockIdx.y;
  const int w = blockIdx.x * 256 + threadIdx.x;
  float m = -3.0e38f;
#pragma unroll
  for (int c = 0; c < 8; ++c) m = fmaxf(m, part[((long)b * 8 + c) * 512 + w]);
  pooled[b * 512 + w] = m;
}

// ---------------- masked transpose to output h [B,512,T] fp32 ----------------
__global__ __launch_bounds__(256)
void tout_k(const float* __restrict__ hm, const float* __restrict__ mask, float* __restrict__ outh)
{
  __shared__ float tile[64][65];
  const int t0 = blockIdx.x * 64, w0 = blockIdx.y * 64, b = blockIdx.z;
  const int tx = threadIdx.x & 63, ty = threadIdx.x >> 6;
  for (int i = ty; i < 64; i += 4)
    tile[i][tx] = hm[((long)b * 1024 + t0 + i) * 512 + w0 + tx];
  __syncthreads();
  const float mv = mask[b * 1024 + t0 + tx];
  for (int i = ty; i < 64; i += 4)
    outh[((long)b * 512 + w0 + i) * 1024 + t0 + tx] = tile[tx][i] * mv;
}

// ---------------- aggregator matmuls: split-K partials + combine ----------------
__global__ __launch_bounds__(256)
void agg1p_k(const float* __restrict__ pooled, const float* __restrict__ wf,
             float* __restrict__ part)
{
  const int b = blockIdx.z, kc = blockIdx.y;
  const int n = blockIdx.x * 256 + threadIdx.x;
  float acc = 0.f;
  const int k0 = kc * 64;
#pragma unroll 8
  for (int k = 0; k < 64; ++k) acc += pooled[b * 512 + k0 + k] * wf[(long)(k0 + k) * 2048 + n];
  part[((long)b * 8 + kc) * 2048 + n] = acc;
}
__global__ __launch_bounds__(256)
void agg1c_k(const float* __restrict__ part, const float* __restrict__ bf_,
             float* __restrict__ z1)
{
  const int b = blockIdx.y;
  const int n = blockIdx.x * 256 + threadIdx.x;
  float acc = 0.f;
#pragma unroll
  for (int c = 0; c < 8; ++c) acc += part[((long)b * 8 + c) * 2048 + n];
  z1[(long)b * 2048 + n] = gelu_f(acc + bf_[n]);
}
__global__ __launch_bounds__(256)
void agg2p_k(const float* __restrict__ z1, const float* __restrict__ wp,
             float* __restrict__ part)
{
  const int b = blockIdx.z, kc = blockIdx.y;
  const int n = blockIdx.x * 256 + threadIdx.x;
  float acc = 0.f;
  const int k0 = kc * 256;
#pragma unroll 8
  for (int k = 0; k < 256; ++k) acc += z1[(long)b * 2048 + k0 + k] * wp[(long)(k0 + k) * 512 + n];
  part[((long)b * 8 + kc) * 512 + n] = acc;
}
__global__ __launch_bounds__(256)
void agg2c_k(const float* __restrict__ part, const float* __restrict__ bp,
             float* __restrict__ zo)
{
  const int b = blockIdx.y;
  const int n = blockIdx.x * 256 + threadIdx.x;
  float acc = 0.f;
#pragma unroll
  for (int c = 0; c < 8; ++c) acc += part[((long)b * 8 + c) * 512 + n];
  zo[b * 512 + n] = acc + bp[n];
}

extern "C" void kernel_launch(void* const* d_in, const int* in_sizes, int n_in,
                              void* d_out, int out_size, void* d_ws, size_t ws_size,
                              hipStream_t stream)
{
  (void)in_sizes; (void)n_in; (void)out_size; (void)ws_size;
  const float* x        = (const float*)d_in[0];
  const float* params   = (const float*)d_in[1];
  const float* mask     = (const float*)d_in[2];
  const float* class_emb= (const float*)d_in[3];
  const float* w_in     = (const float*)d_in[4];
  const float* b_in     = (const float*)d_in[5];
  const float* ln_pre_g = (const float*)d_in[6];
  const float* ln_pre_b = (const float*)d_in[7];
  const float* qkv_w    = (const float*)d_in[8];
  const float* qkv_b    = (const float*)d_in[9];
  const float* attn_pw  = (const float*)d_in[10];
  const float* attn_pb  = (const float*)d_in[11];
  const float* ln1_g    = (const float*)d_in[12];
  const float* ln1_b    = (const float*)d_in[13];
  const float* fc_w     = (const float*)d_in[14];
  const float* fc_b     = (const float*)d_in[15];
  const float* fcp_w    = (const float*)d_in[16];
  const float* fcp_b    = (const float*)d_in[17];
  const float* ln2_g    = (const float*)d_in[18];
  const float* ln2_b    = (const float*)d_in[19];
  const float* ln_post_g= (const float*)d_in[20];
  const float* ln_post_b= (const float*)d_in[21];
  const float* w_out    = (const float*)d_in[22];
  const float* b_out    = (const float*)d_in[23];
  const float* agg_fc_w = (const float*)d_in[24];
  const float* agg_fc_b = (const float*)d_in[25];
  const float* agg_pw   = (const float*)d_in[26];
  const float* agg_pb   = (const float*)d_in[27];

  float* out_f = (float*)d_out;          // z: [0, 16384)
  float* out_h = out_f + 16384;          // h: 64 MiB fp32 region
  u16* sc = (u16*)out_h;                 // bf16 scratch: Q|K [32768x1024] or FF-mid rows [0,16K)

  // ---- workspace layout (~181 MiB) ----
  char* ws = (char*)d_ws;
  float* hf = (float*)ws;       ws += (size_t)32768 * 512 * 4;
  u16* hn = (u16*)ws;           ws += (size_t)32768 * 512 * 2;
  float* E = (float*)ws;        ws += (size_t)1024 * 512 * 4;
  u16* ce_b = (u16*)ws;         ws += (size_t)1024 * 1024 * 2;
  u16* wt_qkv = (u16*)ws;       ws += (size_t)2 * 1536 * 512 * 2;   // double-buffered
  u16* wt_pw  = (u16*)ws;       ws += (size_t)2 * 512 * 512 * 2;
  u16* wt_fc  = (u16*)ws;       ws += (size_t)2 * 2048 * 512 * 2;
  u16* wt_fcp = (u16*)ws;       ws += (size_t)2 * 512 * 2048 * 2;
  u16* w_in_t = (u16*)ws;       ws += (size_t)512 * 1024 * 2;
  u16* w_out_t= (u16*)ws;       ws += (size_t)512 * 512 * 2;
  float* pooled = (float*)ws;   ws += (size_t)32 * 512 * 4;
  float* z1     = (float*)ws;   ws += (size_t)32 * 2048 * 4;
  float* part   = (float*)ws;   ws += (size_t)32 * 8 * 512 * 4;
  float* apart1 = (float*)ws;   ws += (size_t)32 * 8 * 2048 * 4;
  float* apart2 = (float*)ws;   ws += (size_t)32 * 8 * 512 * 4;
  u16* buf2     = (u16*)ws;     ws += (size_t)16384 * 2048 * 2;     // 64 MiB: FF-mid rows [16K,32K)
  u16* vt = buf2;               // V^T full batch (32 MiB) aliases buf2 (time-disjoint)

  const size_t SQ = (size_t)1536 * 512, SP = (size_t)512 * 512;
  const size_t SF = (size_t)2048 * 512, SG = (size_t)512 * 2048;

  // one-time converts + class-emb projection + fused embed+ln_pre
  cast_k<<<1024, 256, 0, stream>>>(class_emb, ce_b, 1024 * 1024);
  tr_k<<<dim3(16, 32), 256, 0, stream>>>(w_in + 9 * 512, w_in_t, 1024, 512);
  tr_k<<<dim3(16, 16), 256, 0, stream>>>(w_out, w_out_t, 512, 512);
  gemm_bt<0><<<dim3(4, 4), 512, 0, stream>>>(ce_b, nullptr, w_in_t, nullptr, E, nullptr, nullptr,
                                             1024, 1024, 1024, 512);
  embed_ln_k<<<32768, 256, 0, stream>>>(x, params, E, w_in, b_in, ln_pre_g, ln_pre_b, hf);
  // layer-0 weight transpose into set 0
  trL_k<<<3072, 256, 0, stream>>>(qkv_w, attn_pw, fc_w, fcp_w,
                                  wt_qkv, wt_pw, wt_fc, wt_fcp);

  for (int l = 0; l < 12; ++l) {
    const size_t cs = (size_t)(l & 1), ns = (size_t)((l + 1) & 1);

    // LN1 full batch -> hn (bf16)
    ln_k<1><<<8192, 256, 0, stream>>>(hf, ln1_g + l * 512, ln1_b + l * 512, hn);
    // QKV full batch (Q|K packed -> sc, V^T -> vt) + attention full batch (out -> hn)
    gemm_bt<4><<<dim3(12, 128), 512, 0, stream>>>(hn, nullptr, wt_qkv + cs * SQ, qkv_b + l * 1536,
                                                  nullptr, sc, vt, 512, 512, 512, 1024);
    attn_k<<<1024, 1024, 0, stream>>>(sc, vt, hn);
    // attn projection full batch: h += hn @ pw^T + b
    gemm_bt<2><<<dim3(4, 128), 512, 0, stream>>>(hn, nullptr, wt_pw + cs * SP, attn_pb + l * 512,
                                                 hf, nullptr, nullptr, 512, 512, 512, 512);
    // LN2 full batch -> hn, fused with next layer's weight transpose (into set ns)
    if (l < 11) {
      ln2trL_k<<<11264, 256, 0, stream>>>(hf, ln2_g + l * 512, ln2_b + l * 512, hn,
                                          qkv_w + (size_t)(l + 1) * 512 * 1536,
                                          attn_pw + (size_t)(l + 1) * 512 * 512,
                                          fc_w + (size_t)(l + 1) * 512 * 2048,
                                          fcp_w + (size_t)(l + 1) * 2048 * 512,
                                          wt_qkv + ns * SQ, wt_pw + ns * SP,
                                          wt_fc + ns * SF, wt_fcp + ns * SG);
    } else {
      ln_k<1><<<8192, 256, 0, stream>>>(hf, ln2_g + l * 512, ln2_b + l * 512, hn);
    }
    // FF full batch: fc (gelu, split-write sc/buf2) then fcp (256x128 8-wave, split-read,
    // residual into hf)
    gemm_bt2<5><<<dim3(8, 128), 1024, 0, stream>>>(hn, wt_fc + cs * SF, fc_b + l * 2048,
                                                   nullptr, sc, buf2, 512, 512, 512, 2048);
    gemm_bt<2><<<dim3(4, 128), 512, 0, stream>>>(sc, buf2, wt_fcp + cs * SG, fcp_b + l * 512,
                                                 hf, nullptr, nullptr, 2048, 2048, 2048, 512);
  }

  // final LN + out-proj, then pool/agg, then h output
  ln_k<1><<<8192, 256, 0, stream>>>(hf, ln_post_g, ln_post_b, hn);
  gemm_bt<0><<<dim3(4, 128), 512, 0, stream>>>(hn, nullptr, w_out_t, b_out, hf, nullptr, nullptr,
                                               512, 512, 512, 512);
  pool1_k<<<dim3(8, 32), 256, 0, stream>>>(hf, mask, part);
  pool2_k<<<dim3(2, 32), 256, 0, stream>>>(part, pooled);
  agg1p_k<<<dim3(8, 8, 32), 256, 0, stream>>>(pooled, agg_fc_w, apart1);
  agg1c_k<<<dim3(8, 32), 256, 0, stream>>>(apart1, agg_fc_b, z1);
  agg2p_k<<<dim3(2, 8, 32), 256, 0, stream>>>(z1, agg_pw, apart2);
  agg2c_k<<<dim3(2, 32), 256, 0, stream>>>(apart2, agg_pb, out_f);
  tout_k<<<dim3(16, 8, 32), 256, 0, stream>>>(hf, mask, out_h);
}